// Round 1
// baseline (3603.176 us; speedup 1.0000x reference)
//
#include <hip/hip_runtime.h>
#include <hip/hip_bf16.h>

// Performer (FAVOR+) causal linear self-attention, MI355X round 0.
// B=4 L=4096 E=512 H=8 D=64 M=256 chunk=256.
// Pipeline: qkv head-split+proj -> phi(q),phi(k) [bf16] -> chunked causal scan -> out proj.

#define BB 4
#define LL 4096
#define EE 512
#define HH 8
#define DD 64
#define MM 256
#define CC 256
#define NCH 16   // L / CC
#define BHN 32   // B * H

constexpr float DN    = 0.35355339059327373f; // 64^-0.25
constexpr float DIAGC = 0.0625f;              // 0.5 * dn^2
constexpr float RATIO = 0.0625f;              // 256^-0.5
constexpr float EPSV  = 1e-4f;

__device__ __forceinline__ unsigned short f2bf(float f){
  unsigned u = __float_as_uint(f);
  u = u + 0x7FFFu + ((u >> 16) & 1u);   // RTNE
  return (unsigned short)(u >> 16);
}
__device__ __forceinline__ float bfl(unsigned u){ return __uint_as_float(u << 16); }
__device__ __forceinline__ float bfh(unsigned u){ return __uint_as_float(u & 0xFFFF0000u); }
// order-preserving f32 <-> u32 encoding for atomicMax
__device__ __forceinline__ unsigned enc_f32(float f){
  unsigned u = __float_as_uint(f);
  return (u & 0x80000000u) ? ~u : (u | 0x80000000u);
}
__device__ __forceinline__ float dec_f32(unsigned u){
  unsigned v = (u & 0x80000000u) ? (u & 0x7FFFFFFFu) : ~u;
  return __uint_as_float(v);
}

// ---------------- K1: head-split + per-head DxD projection ----------------
// x:[B,L,E], W:[D,D] row-major; out:[BH, L, D] with out[(bh*L+l)*D+d] = sum_dp x[b,l,h*D+dp] * W[d*D+dp]
__global__ __launch_bounds__(256) void k_transform(const float* __restrict__ x,
                                                   const float* __restrict__ W,
                                                   float* __restrict__ out){
  __shared__ float Wt[DD * 65];   // transposed, padded: Wt[dp*65+d] = W[d][dp]
  __shared__ float xr[4][DD];
  int tid = threadIdx.x;
  for (int i = tid; i < DD * DD; i += 256){
    int d = i >> 6, dp = i & 63;
    Wt[dp * 65 + d] = W[i];
  }
  int bh = blockIdx.x >> 10;            // / (L/4)
  int l0 = (blockIdx.x & 1023) << 2;
  int b = bh >> 3, h = bh & 7;
  int r = tid >> 6, d = tid & 63;
  xr[r][d] = x[((size_t)(b * LL + l0 + r)) * EE + h * DD + d];
  __syncthreads();
  float acc = 0.f;
  #pragma unroll
  for (int dp = 0; dp < DD; ++dp)
    acc += xr[r][dp] * Wt[dp * 65 + d];
  out[((size_t)(bh * LL + l0 + r)) * DD + d] = acc;
}

// ---------------- K2: global max of dn * (k' . proj_m) over all rows, m ----------------
// wave-per-row; lane handles m = lane*4 + mi (matches projP layout)
__global__ __launch_bounds__(256) void k_kmax(const float* __restrict__ xh,
                                              const float* __restrict__ proj,
                                              unsigned* __restrict__ kout){
  __shared__ float projP[DD * MM];  // projP[dp*256 + mi*64 + lane] = proj[(lane*4+mi)*64 + dp]
  __shared__ float red[4];
  int tid = threadIdx.x;
  for (int i = tid; i < DD * MM; i += 256){
    int dp = i >> 8, r = i & 255, mi = r >> 6, ln = r & 63;
    projP[i] = proj[(ln * 4 + mi) * DD + dp];
  }
  __syncthreads();
  int w = tid >> 6, lane = tid & 63;
  float wmax = -3.0e38f;
  for (int g = blockIdx.x; g < (BHN * LL) / 4; g += gridDim.x){
    size_t row = (size_t)g * 4 + w;
    float xv = xh[row * DD + lane];
    float d0 = 0, d1 = 0, d2 = 0, d3 = 0;
    #pragma unroll
    for (int dp = 0; dp < DD; ++dp){
      float kv = __shfl(xv, dp, 64);
      d0 += kv * projP[dp * MM +   0 + lane];
      d1 += kv * projP[dp * MM +  64 + lane];
      d2 += kv * projP[dp * MM + 128 + lane];
      d3 += kv * projP[dp * MM + 192 + lane];
    }
    wmax = fmaxf(wmax, fmaxf(fmaxf(d0, d1), fmaxf(d2, d3)));
  }
  wmax *= DN;  // DN > 0: max commutes
  #pragma unroll
  for (int off = 32; off >= 1; off >>= 1)
    wmax = fmaxf(wmax, __shfl_xor(wmax, off, 64));
  if (lane == 0) red[w] = wmax;
  __syncthreads();
  if (tid == 0){
    float m = fmaxf(fmaxf(red[0], red[1]), fmaxf(red[2], red[3]));
    atomicMax(kout, enc_f32(m));
  }
}

// ---------------- K3: phi = ratio*(exp(xd - diag - m) + eps) -> bf16 ----------------
__global__ __launch_bounds__(256) void k_phi(const float* __restrict__ xh,
                                             const float* __restrict__ proj,
                                             const unsigned* __restrict__ kmaxp,
                                             unsigned short* __restrict__ phi,
                                             int is_query){
  __shared__ float projP[DD * MM];
  int tid = threadIdx.x;
  for (int i = tid; i < DD * MM; i += 256){
    int dp = i >> 8, r = i & 255, mi = r >> 6, ln = r & 63;
    projP[i] = proj[(ln * 4 + mi) * DD + dp];
  }
  __syncthreads();
  int w = tid >> 6, lane = tid & 63;
  float gm = is_query ? 0.f : dec_f32(*kmaxp);
  for (int g = blockIdx.x; g < (BHN * LL) / 4; g += gridDim.x){
    size_t row = (size_t)g * 4 + w;
    float xv = xh[row * DD + lane];
    float sq = xv * xv;
    #pragma unroll
    for (int off = 32; off >= 1; off >>= 1)
      sq += __shfl_xor(sq, off, 64);
    float diag = DIAGC * sq;
    float d0 = 0, d1 = 0, d2 = 0, d3 = 0;
    #pragma unroll
    for (int dp = 0; dp < DD; ++dp){
      float kv = __shfl(xv, dp, 64);
      d0 += kv * projP[dp * MM +   0 + lane];
      d1 += kv * projP[dp * MM +  64 + lane];
      d2 += kv * projP[dp * MM + 128 + lane];
      d3 += kv * projP[dp * MM + 192 + lane];
    }
    float xd0 = DN * d0, xd1 = DN * d1, xd2 = DN * d2, xd3 = DN * d3;
    float mval;
    if (is_query){
      float mx = fmaxf(fmaxf(xd0, xd1), fmaxf(xd2, xd3));
      #pragma unroll
      for (int off = 32; off >= 1; off >>= 1)
        mx = fmaxf(mx, __shfl_xor(mx, off, 64));
      mval = mx;
    } else {
      mval = gm;
    }
    float bsub = diag + mval;
    ushort4 pk;
    pk.x = f2bf(RATIO * (expf(xd0 - bsub) + EPSV));
    pk.y = f2bf(RATIO * (expf(xd1 - bsub) + EPSV));
    pk.z = f2bf(RATIO * (expf(xd2 - bsub) + EPSV));
    pk.w = f2bf(RATIO * (expf(xd3 - bsub) + EPSV));
    *reinterpret_cast<ushort4*>(phi + row * MM + lane * 4) = pk;  // m = lane*4 + mi
  }
}

// ---------------- K4: per-chunk S_c[m,d] = sum_j kp[j,m] v[j,d]; z_c[m] = sum_j kp[j,m] ----
__global__ __launch_bounds__(256) void k_chunkKV(const unsigned short* __restrict__ kp,
                                                 const float* __restrict__ vh,
                                                 float* __restrict__ S,
                                                 float* __restrict__ z){
  __shared__ float vL[CC][DD];   // 64 KiB
  int blk = blockIdx.x, tid = threadIdx.x;   // blk = bh*NCH + c; chunk rows = blk*CC ..
  size_t row0 = (size_t)blk * CC;
  for (int i = tid; i < CC * DD; i += 256)
    vL[i >> 6][i & 63] = vh[row0 * DD + i];
  __syncthreads();
  float acc[DD];
  #pragma unroll
  for (int d = 0; d < DD; ++d) acc[d] = 0.f;
  float zz = 0.f;
  for (int j = 0; j < CC; ++j){
    float kv = bfl((unsigned)kp[(row0 + j) * MM + tid]);
    zz += kv;
    const float4* vr = reinterpret_cast<const float4*>(&vL[j][0]);
    #pragma unroll
    for (int d4 = 0; d4 < 16; ++d4){
      float4 vv = vr[d4];
      acc[d4 * 4 + 0] += kv * vv.x;
      acc[d4 * 4 + 1] += kv * vv.y;
      acc[d4 * 4 + 2] += kv * vv.z;
      acc[d4 * 4 + 3] += kv * vv.w;
    }
  }
  float4* sp = reinterpret_cast<float4*>(S + ((size_t)blk * MM + tid) * DD);
  #pragma unroll
  for (int d4 = 0; d4 < 16; ++d4){
    float4 vv; vv.x = acc[d4*4+0]; vv.y = acc[d4*4+1]; vv.z = acc[d4*4+2]; vv.w = acc[d4*4+3];
    sp[d4] = vv;
  }
  z[(size_t)blk * MM + tid] = zz;
}

// ---------------- K5: in-place exclusive prefix over the NCH chunk planes ----------------
__global__ __launch_bounds__(256) void k_prefix(float* __restrict__ buf, int per_bh){
  int idx = blockIdx.x * 256 + threadIdx.x;
  if (idx >= BHN * per_bh) return;
  int bh = idx / per_bh, r = idx % per_bh;
  size_t base = (size_t)bh * NCH * per_bh + r;
  float run = 0.f;
  #pragma unroll
  for (int c = 0; c < NCH; ++c){
    size_t a = base + (size_t)c * per_bh;
    float t = buf[a];
    buf[a] = run;
    run += t;
  }
}

// ---------------- K6: per-chunk causal attention ----------------
// thread i owns output row i of the chunk. kp chunk staged in LDS (bf16, 128 KiB).
__global__ __launch_bounds__(256, 1) void k_attn(const unsigned short* __restrict__ qp,
                                                 const unsigned short* __restrict__ kp,
                                                 const float* __restrict__ vh,
                                                 const float* __restrict__ Spre,
                                                 const float* __restrict__ zpre,
                                                 float* __restrict__ attn){
  __shared__ unsigned kpL[CC * (MM / 2)];   // 128 KiB, kpL[j*128 + t] = 2 bf16 (m=2t, 2t+1)
  int blk = blockIdx.x, tid = threadIdx.x;
  size_t row0 = (size_t)blk * CC;
  const unsigned* kpu = reinterpret_cast<const unsigned*>(kp) + row0 * (MM / 2);
  for (int i = tid; i < CC * (MM / 2); i += 256) kpL[i] = kpu[i];
  __syncthreads();
  int i = tid;
  uint4 q4[32];   // own qp row, 256 bf16 in 128 VGPRs (all accesses fully unrolled)
  const uint4* qr = reinterpret_cast<const uint4*>(
      reinterpret_cast<const unsigned*>(qp) + (row0 + i) * (MM / 2));
  #pragma unroll
  for (int t = 0; t < 32; ++t) q4[t] = qr[t];
  float num[DD];
  #pragma unroll
  for (int d = 0; d < DD; ++d) num[d] = 0.f;
  float den = 0.f;
  const float4* vbase = reinterpret_cast<const float4*>(vh + row0 * DD);
  // triangular scores pass: j <= i
  for (int j = 0; j <= i; ++j){
    const uint4* kr = reinterpret_cast<const uint4*>(&kpL[j * (MM / 2)]);
    float s = 0.f;
    #pragma unroll
    for (int t = 0; t < 32; ++t){
      uint4 a = q4[t];
      uint4 b = kr[t];
      s += bfl(a.x) * bfl(b.x) + bfh(a.x) * bfh(b.x);
      s += bfl(a.y) * bfl(b.y) + bfh(a.y) * bfh(b.y);
      s += bfl(a.z) * bfl(b.z) + bfh(a.z) * bfh(b.z);
      s += bfl(a.w) * bfl(b.w) + bfh(a.w) * bfh(b.w);
    }
    den += s;
    const float4* vr = vbase + j * 16;
    #pragma unroll
    for (int d4 = 0; d4 < 16; ++d4){
      float4 vv = vr[d4];
      num[d4 * 4 + 0] += s * vv.x;
      num[d4 * 4 + 1] += s * vv.y;
      num[d4 * 4 + 2] += s * vv.z;
      num[d4 * 4 + 3] += s * vv.w;
    }
  }
  // prefix-state pass: num += qp_i . Spre ; den += qp_i . zpre
  const unsigned short* qprow = qp + (row0 + i) * MM;
  const float* Sp = Spre + (size_t)blk * MM * DD;
  const float* zp = zpre + (size_t)blk * MM;
  for (int m = 0; m < MM; ++m){
    float qv = bfl((unsigned)qprow[m]);
    den += qv * zp[m];
    const float4* sr = reinterpret_cast<const float4*>(Sp + (size_t)m * DD);
    #pragma unroll
    for (int d4 = 0; d4 < 16; ++d4){
      float4 vv = sr[d4];
      num[d4 * 4 + 0] += qv * vv.x;
      num[d4 * 4 + 1] += qv * vv.y;
      num[d4 * 4 + 2] += qv * vv.z;
      num[d4 * 4 + 3] += qv * vv.w;
    }
  }
  float inv = 1.f / den;
  int bh = blk >> 4, c = blk & 15;
  int b = bh >> 3, h = bh & 7;
  float4* op = reinterpret_cast<float4*>(
      attn + ((size_t)(b * LL + c * CC + i)) * EE + h * DD);
  #pragma unroll
  for (int d4 = 0; d4 < 16; ++d4){
    float4 vv;
    vv.x = num[d4*4+0] * inv; vv.y = num[d4*4+1] * inv;
    vv.z = num[d4*4+2] * inv; vv.w = num[d4*4+3] * inv;
    op[d4] = vv;
  }
}

// ---------------- K7: out = attn[BL,E] @ Wout^T + bout ----------------
__global__ __launch_bounds__(256) void k_proj(const float* __restrict__ attn,
                                              const float* __restrict__ Wout,
                                              const float* __restrict__ bout,
                                              float* __restrict__ out){
  __shared__ float As[64][65];
  __shared__ float Bs[64][65];   // Bs[kk][e]
  int rb = blockIdx.x >> 3, eb = blockIdx.x & 7;
  int r0 = rb * 64, e0 = eb * 64;
  int tid = threadIdx.x;
  int tx = tid & 15, ty = tid >> 4;
  float acc[4][4] = {};
  for (int k0 = 0; k0 < EE; k0 += 64){
    __syncthreads();
    for (int idx = tid; idx < 4096; idx += 256){
      int r = idx >> 6, kk = idx & 63;
      As[r][kk] = attn[(size_t)(r0 + r) * EE + k0 + kk];
    }
    for (int idx = tid; idx < 4096; idx += 256){
      int e = idx >> 6, kk = idx & 63;
      Bs[kk][e] = Wout[(size_t)(e0 + e) * EE + k0 + kk];
    }
    __syncthreads();
    #pragma unroll 8
    for (int kk = 0; kk < 64; ++kk){
      float a[4], b[4];
      #pragma unroll
      for (int ii = 0; ii < 4; ++ii) a[ii] = As[ty * 4 + ii][kk];
      #pragma unroll
      for (int jj = 0; jj < 4; ++jj) b[jj] = Bs[kk][jj * 16 + tx];
      #pragma unroll
      for (int ii = 0; ii < 4; ++ii)
        #pragma unroll
        for (int jj = 0; jj < 4; ++jj)
          acc[ii][jj] += a[ii] * b[jj];
    }
  }
  #pragma unroll
  for (int ii = 0; ii < 4; ++ii){
    int r = r0 + ty * 4 + ii;
    #pragma unroll
    for (int jj = 0; jj < 4; ++jj){
      int e = e0 + jj * 16 + tx;
      out[(size_t)r * EE + e] = acc[ii][jj] + bout[e];
    }
  }
}

extern "C" void kernel_launch(void* const* d_in, const int* in_sizes, int n_in,
                              void* d_out, int out_size, void* d_ws, size_t ws_size,
                              hipStream_t stream){
  const float* queries = (const float*)d_in[0];
  const float* keys    = (const float*)d_in[1];
  const float* values  = (const float*)d_in[2];
  const float* Wq      = (const float*)d_in[3];
  const float* Wk      = (const float*)d_in[4];
  const float* Wv      = (const float*)d_in[5];
  const float* Wout    = (const float*)d_in[6];
  const float* bout    = (const float*)d_in[7];
  const float* proj    = (const float*)d_in[8];

  // workspace layout (bytes); total ~225 MiB with aliasing
  char* ws = (char*)d_ws;
  float*          qh   = (float*)(ws + 0);             // 33,554,432  [BH,L,D]
  float*          kh   = (float*)(ws + 33554432);      // 33,554,432
  float*          vh   = (float*)(ws + 67108864);      // 33,554,432
  unsigned short* qp   = (unsigned short*)(ws + 100663296);  // 67,108,864  [BH,L,M] bf16
  unsigned short* kp   = (unsigned short*)(ws + 167772160);  // 67,108,864
  float*          z    = (float*)(ws + 234881024);     // 524,288     [BH,NCH,M]
  unsigned*       kmax = (unsigned*)(ws + 235405312);  // 4
  float*          S    = qh;   // qh dead after k_phi(qh); S written by k_chunkKV
  float*          attn = kh;   // kh dead after k_phi(kh); attn written by k_attn
  float*          out  = (float*)d_out;

  hipMemsetAsync(kmax, 0, 4, stream);   // order-preserving encoding: 0 < enc(x) for all finite x

  k_transform<<<dim3(BHN * LL / 4), dim3(256), 0, stream>>>(queries, Wq, qh);
  k_transform<<<dim3(BHN * LL / 4), dim3(256), 0, stream>>>(keys,    Wk, kh);
  k_transform<<<dim3(BHN * LL / 4), dim3(256), 0, stream>>>(values,  Wv, vh);

  k_kmax<<<dim3(2048), dim3(256), 0, stream>>>(kh, proj, kmax);

  k_phi<<<dim3(2048), dim3(256), 0, stream>>>(qh, proj, kmax, qp, 1);
  k_phi<<<dim3(2048), dim3(256), 0, stream>>>(kh, proj, kmax, kp, 0);

  k_chunkKV<<<dim3(BHN * NCH), dim3(256), 0, stream>>>(kp, vh, S, z);

  k_prefix<<<dim3((BHN * MM * DD) / 256), dim3(256), 0, stream>>>(S, MM * DD);
  k_prefix<<<dim3((BHN * MM) / 256), dim3(256), 0, stream>>>(z, MM);

  k_attn<<<dim3(BHN * NCH), dim3(256), 0, stream>>>(qp, kp, vh, S, z, attn);

  k_proj<<<dim3((BB * LL / 64) * (EE / 64)), dim3(256), 0, stream>>>(attn, Wout, bout, out);
}

// Round 2
// 2311.369 us; speedup vs baseline: 1.5589x; 1.5589x over previous
//
#include <hip/hip_runtime.h>
#include <hip/hip_bf16.h>

// Performer (FAVOR+) causal linear self-attention, MI355X round 1.
// B=4 L=4096 E=512 H=8 D=64 M=256 chunk=256.
// Round 1: MFMA chunk-attention (k_cattn) replaces the 1790us scalar k_attn.

#define BB 4
#define LL 4096
#define EE 512
#define HH 8
#define DD 64
#define MM 256
#define CC 256
#define NCH 16   // L / CC
#define BHN 32   // B * H

constexpr float DN    = 0.35355339059327373f; // 64^-0.25
constexpr float DIAGC = 0.0625f;              // 0.5 * dn^2
constexpr float RATIO = 0.0625f;              // 256^-0.5
constexpr float EPSV  = 1e-4f;

typedef __attribute__((ext_vector_type(8))) short bf16x8;
typedef __attribute__((ext_vector_type(4))) float f32x4;
union FU { uint4 u; bf16x8 b; };
__device__ __forceinline__ bf16x8 asb(uint4 u){ FU f; f.u = u; return f.b; }
union PK2 { ushort4 s; uint2 u; };
union PK8 { unsigned short s[8]; uint4 u; };

__device__ __forceinline__ unsigned short f2bf(float f){
  unsigned u = __float_as_uint(f);
  u = u + 0x7FFFu + ((u >> 16) & 1u);   // RTNE
  return (unsigned short)(u >> 16);
}
__device__ __forceinline__ float bfl(unsigned u){ return __uint_as_float(u << 16); }
__device__ __forceinline__ float bfh(unsigned u){ return __uint_as_float(u & 0xFFFF0000u); }
__device__ __forceinline__ unsigned enc_f32(float f){
  unsigned u = __float_as_uint(f);
  return (u & 0x80000000u) ? ~u : (u | 0x80000000u);
}
__device__ __forceinline__ float dec_f32(unsigned u){
  unsigned v = (u & 0x80000000u) ? (u & 0x7FFFFFFFu) : ~u;
  return __uint_as_float(v);
}

// ---------------- K1: head-split + per-head DxD projection (f32 out, for q,k) ----------------
__global__ __launch_bounds__(256) void k_transform(const float* __restrict__ x,
                                                   const float* __restrict__ W,
                                                   float* __restrict__ out){
  __shared__ float Wt[DD * 65];   // Wt[dp*65+d] = W[d][dp]
  __shared__ float xr[4][DD];
  int tid = threadIdx.x;
  for (int i = tid; i < DD * DD; i += 256){
    int d = i >> 6, dp = i & 63;
    Wt[dp * 65 + d] = W[i];
  }
  int bh = blockIdx.x >> 10;
  int l0 = (blockIdx.x & 1023) << 2;
  int b = bh >> 3, h = bh & 7;
  int r = tid >> 6, d = tid & 63;
  xr[r][d] = x[((size_t)(b * LL + l0 + r)) * EE + h * DD + d];
  __syncthreads();
  float acc = 0.f;
  #pragma unroll
  for (int dp = 0; dp < DD; ++dp)
    acc += xr[r][dp] * Wt[dp * 65 + d];
  out[((size_t)(bh * LL + l0 + r)) * DD + d] = acc;
}

// ---------------- K1v: v transform -> transposed bf16 vT [BH][D][L] ----------------
__global__ __launch_bounds__(256) void k_transform_vT(const float* __restrict__ x,
                                                      const float* __restrict__ W,
                                                      unsigned short* __restrict__ vTb){
  __shared__ float Wt[DD * 65];
  __shared__ float T[64 * 65];     // T[l][d], stride 65
  int tid = threadIdx.x;
  for (int i = tid; i < DD * DD; i += 256){
    int d = i >> 6, dp = i & 63;
    Wt[dp * 65 + d] = W[i];
  }
  __syncthreads();
  int bh = blockIdx.x >> 6;               // grid = BH * (L/64)
  int l0 = (blockIdx.x & 63) << 6;
  int b = bh >> 3, h = bh & 7;
  int r = tid >> 6, lane = tid & 63;      // wave r handles rows g*4+r
  for (int g = 0; g < 16; ++g){
    int l = g * 4 + r;
    float xv = x[((size_t)(b * LL + l0 + l)) * EE + h * DD + lane];
    float acc = 0.f;
    #pragma unroll
    for (int dp = 0; dp < DD; ++dp)
      acc += __shfl(xv, dp, 64) * Wt[dp * 65 + lane];
    T[l * 65 + lane] = acc;
  }
  __syncthreads();
  int dd = tid >> 2, e0 = (tid & 3) << 4;
  PK8 p0, p1;
  #pragma unroll
  for (int jj = 0; jj < 8; ++jj){
    p0.s[jj] = f2bf(T[(e0 + jj) * 65 + dd]);
    p1.s[jj] = f2bf(T[(e0 + 8 + jj) * 65 + dd]);
  }
  uint4* op = reinterpret_cast<uint4*>(vTb + ((size_t)(bh * DD + dd)) * LL + l0 + e0);
  op[0] = p0.u;
  op[1] = p1.u;
}

// ---------------- K2: global max of dn * (k' . proj_m) ----------------
__global__ __launch_bounds__(256) void k_kmax(const float* __restrict__ xh,
                                              const float* __restrict__ proj,
                                              unsigned* __restrict__ kout){
  __shared__ float projP[DD * MM];
  __shared__ float red[4];
  int tid = threadIdx.x;
  for (int i = tid; i < DD * MM; i += 256){
    int dp = i >> 8, r = i & 255, mi = r >> 6, ln = r & 63;
    projP[i] = proj[(ln * 4 + mi) * DD + dp];
  }
  __syncthreads();
  int w = tid >> 6, lane = tid & 63;
  float wmax = -3.0e38f;
  for (int g = blockIdx.x; g < (BHN * LL) / 4; g += gridDim.x){
    size_t row = (size_t)g * 4 + w;
    float xv = xh[row * DD + lane];
    float d0 = 0, d1 = 0, d2 = 0, d3 = 0;
    #pragma unroll
    for (int dp = 0; dp < DD; ++dp){
      float kv = __shfl(xv, dp, 64);
      d0 += kv * projP[dp * MM +   0 + lane];
      d1 += kv * projP[dp * MM +  64 + lane];
      d2 += kv * projP[dp * MM + 128 + lane];
      d3 += kv * projP[dp * MM + 192 + lane];
    }
    wmax = fmaxf(wmax, fmaxf(fmaxf(d0, d1), fmaxf(d2, d3)));
  }
  wmax *= DN;
  #pragma unroll
  for (int off = 32; off >= 1; off >>= 1)
    wmax = fmaxf(wmax, __shfl_xor(wmax, off, 64));
  if (lane == 0) red[w] = wmax;
  __syncthreads();
  if (tid == 0){
    float m = fmaxf(fmaxf(red[0], red[1]), fmaxf(red[2], red[3]));
    atomicMax(kout, enc_f32(m));
  }
}

// ---------------- K3: phi -> bf16 [row][m] ----------------
__global__ __launch_bounds__(256) void k_phi(const float* __restrict__ xh,
                                             const float* __restrict__ proj,
                                             const unsigned* __restrict__ kmaxp,
                                             unsigned short* __restrict__ phi,
                                             int is_query){
  __shared__ float projP[DD * MM];
  int tid = threadIdx.x;
  for (int i = tid; i < DD * MM; i += 256){
    int dp = i >> 8, r = i & 255, mi = r >> 6, ln = r & 63;
    projP[i] = proj[(ln * 4 + mi) * DD + dp];
  }
  __syncthreads();
  int w = tid >> 6, lane = tid & 63;
  float gm = is_query ? 0.f : dec_f32(*kmaxp);
  for (int g = blockIdx.x; g < (BHN * LL) / 4; g += gridDim.x){
    size_t row = (size_t)g * 4 + w;
    float xv = xh[row * DD + lane];
    float sq = xv * xv;
    #pragma unroll
    for (int off = 32; off >= 1; off >>= 1)
      sq += __shfl_xor(sq, off, 64);
    float diag = DIAGC * sq;
    float d0 = 0, d1 = 0, d2 = 0, d3 = 0;
    #pragma unroll
    for (int dp = 0; dp < DD; ++dp){
      float kv = __shfl(xv, dp, 64);
      d0 += kv * projP[dp * MM +   0 + lane];
      d1 += kv * projP[dp * MM +  64 + lane];
      d2 += kv * projP[dp * MM + 128 + lane];
      d3 += kv * projP[dp * MM + 192 + lane];
    }
    float xd0 = DN * d0, xd1 = DN * d1, xd2 = DN * d2, xd3 = DN * d3;
    float mval;
    if (is_query){
      float mx = fmaxf(fmaxf(xd0, xd1), fmaxf(xd2, xd3));
      #pragma unroll
      for (int off = 32; off >= 1; off >>= 1)
        mx = fmaxf(mx, __shfl_xor(mx, off, 64));
      mval = mx;
    } else {
      mval = gm;
    }
    float bsub = diag + mval;
    ushort4 pk;
    pk.x = f2bf(RATIO * (expf(xd0 - bsub) + EPSV));
    pk.y = f2bf(RATIO * (expf(xd1 - bsub) + EPSV));
    pk.z = f2bf(RATIO * (expf(xd2 - bsub) + EPSV));
    pk.w = f2bf(RATIO * (expf(xd3 - bsub) + EPSV));
    *reinterpret_cast<ushort4*>(phi + row * MM + lane * 4) = pk;
  }
}

// ---------------- K4: SpT_c[d][m] = sum_j vT[d][j] kp[j][m] (per chunk, transposed) -------
__global__ __launch_bounds__(256) void k_chunkKV_T(const unsigned short* __restrict__ kp,
                                                   const unsigned short* __restrict__ vTb,
                                                   float* __restrict__ SpT){
  __shared__ float vL[64 * 261];   // vL[d*261 + j]
  int blk = blockIdx.x, tid = threadIdx.x;
  int bh = blk >> 4, c = blk & 15;
  for (int i = tid; i < 64 * 256; i += 256){
    int d = i >> 8, j = i & 255;
    unsigned short uv = vTb[((size_t)(bh * DD + d)) * LL + c * CC + j];
    vL[d * 261 + j] = __uint_as_float(((unsigned)uv) << 16);
  }
  __syncthreads();
  int d = tid >> 2, q = tid & 3;
  float acc[64];
  #pragma unroll
  for (int m = 0; m < 64; ++m) acc[m] = 0.f;
  size_t row0 = (size_t)blk * CC;
  const uint4* kpu = reinterpret_cast<const uint4*>(kp);
  for (int j = 0; j < CC; ++j){
    float vv = vL[d * 261 + j];
    const uint4* kr = kpu + (row0 + j) * 32 + q * 8;
    #pragma unroll
    for (int u = 0; u < 8; ++u){
      uint4 kk = kr[u];
      acc[u*8+0] += vv * bfl(kk.x); acc[u*8+1] += vv * bfh(kk.x);
      acc[u*8+2] += vv * bfl(kk.y); acc[u*8+3] += vv * bfh(kk.y);
      acc[u*8+4] += vv * bfl(kk.z); acc[u*8+5] += vv * bfh(kk.z);
      acc[u*8+6] += vv * bfl(kk.w); acc[u*8+7] += vv * bfh(kk.w);
    }
  }
  float4* op = reinterpret_cast<float4*>(SpT + ((size_t)blk * DD + d) * MM + q * 64);
  #pragma unroll
  for (int m4 = 0; m4 < 16; ++m4){
    float4 o;
    o.x = acc[m4*4+0]; o.y = acc[m4*4+1]; o.z = acc[m4*4+2]; o.w = acc[m4*4+3];
    op[m4] = o;
  }
}

// ---------------- K4b: z_c[m] = sum_j kp[j][m] ----------------
__global__ __launch_bounds__(256) void k_chunkZ(const unsigned short* __restrict__ kp,
                                                float* __restrict__ z){
  int blk = blockIdx.x, m = threadIdx.x;
  size_t row0 = (size_t)blk * CC;
  float s = 0.f;
  for (int j = 0; j < CC; ++j) s += bfl((unsigned)kp[(row0 + j) * MM + m]);
  z[(size_t)blk * MM + m] = s;
}

// ---------------- K5: exclusive prefix over chunks -> bf16 ----------------
__global__ __launch_bounds__(256) void k_prefix_b(const float* __restrict__ buf,
                                                  unsigned short* __restrict__ outb,
                                                  int per_bh){
  int idx = blockIdx.x * 256 + threadIdx.x;
  if (idx >= BHN * per_bh) return;
  int bh = idx / per_bh, r = idx - bh * per_bh;
  float run = 0.f;
  #pragma unroll
  for (int c = 0; c < NCH; ++c){
    size_t a = ((size_t)bh * NCH + c) * per_bh + r;
    outb[a] = f2bf(run);
    run += buf[a];
  }
}

// ---------------- K6: MFMA chunk causal attention ----------------
// Block = one (bh, chunk). 8 waves; wave w owns itiles {w, 15-w}.
// Phase 1: S' = kp @ qp^T per tile (triangular), masked bf16 -> swizzled LDS S[i][j].
// Phase 2: out^T = [vT | SpT_ext] @ [S | qp]^T; den via synthesized ones/zpre row (d=64).
__global__ __launch_bounds__(512, 2) void k_cattn(const unsigned short* __restrict__ qp,
                                                  const unsigned short* __restrict__ kp,
                                                  const unsigned short* __restrict__ vTb,
                                                  const unsigned short* __restrict__ Spb,
                                                  const unsigned short* __restrict__ zb,
                                                  float* __restrict__ attn){
  __shared__ unsigned S4[CC * 128];   // 128 KiB: S[i][j] bf16, byte ^= ((i&7)<<4)
  int tid = threadIdx.x;
  int w = tid >> 6, lane = tid & 63;
  int l15 = lane & 15, g = lane >> 4;
  int blk = blockIdx.x;
  int bh = blk >> 4, c = blk & 15;
  int b = bh >> 3, h = bh & 7;
  size_t row0 = (size_t)blk * CC;
  const uint4* qpu = reinterpret_cast<const uint4*>(qp);
  const uint4* kpu = reinterpret_cast<const uint4*>(kp);
  const uint4* vTu = reinterpret_cast<const uint4*>(vTb);
  const uint4* Spu = reinterpret_cast<const uint4*>(Spb);
  const uint4* zbu = reinterpret_cast<const uint4*>(zb);

  int its[2] = { w, 15 - w };
  uint4 qf[2][8];
  #pragma unroll
  for (int t = 0; t < 2; ++t){
    size_t qrow = row0 + its[t] * 16 + l15;
    #pragma unroll
    for (int ks = 0; ks < 8; ++ks)
      qf[t][ks] = qpu[qrow * 32 + ks * 4 + g];
  }

  // ---- phase 1: scores ----
  #pragma unroll
  for (int t = 0; t < 2; ++t){
    int it = its[t];
    int i = it * 16 + l15;
    int jtmax = it | 1;
    for (int jt = 0; jt <= jtmax; ++jt){
      f32x4 acc = {0.f, 0.f, 0.f, 0.f};
      size_t krow = row0 + jt * 16 + l15;
      #pragma unroll
      for (int ks = 0; ks < 8; ++ks){
        uint4 kfu = kpu[krow * 32 + ks * 4 + g];
        acc = __builtin_amdgcn_mfma_f32_16x16x32_bf16(asb(kfu), asb(qf[t][ks]), acc, 0, 0, 0);
      }
      int jb = jt * 16 + g * 4;     // element index of acc[0]
      PK2 pk;
      pk.s.x = (jb + 0 <= i) ? f2bf(acc[0]) : (unsigned short)0;
      pk.s.y = (jb + 1 <= i) ? f2bf(acc[1]) : (unsigned short)0;
      pk.s.z = (jb + 2 <= i) ? f2bf(acc[2]) : (unsigned short)0;
      pk.s.w = (jb + 3 <= i) ? f2bf(acc[3]) : (unsigned short)0;
      int byte = i * 512 + ((jb * 2) ^ ((i & 7) << 4));
      *reinterpret_cast<uint2*>(&S4[byte >> 2]) = pk.u;
    }
  }
  // no barrier: each wave reads only S rows it wrote.

  // ---- phase 2: PV + prefix ----
  uint4 zero4 = {0u, 0u, 0u, 0u};
  uint4 ones4 = {0x3F803F80u, 0x3F803F80u, 0x3F803F80u, 0x3F803F80u};
  #pragma unroll
  for (int t = 0; t < 2; ++t){
    int it = its[t];
    int i = it * 16 + l15;
    f32x4 acc[5];
    #pragma unroll
    for (int a5 = 0; a5 < 5; ++a5) acc[a5] = (f32x4){0.f, 0.f, 0.f, 0.f};
    int ksv = (it >> 1) + 1;
    for (int ks = 0; ks < ksv; ++ks){
      int byte = i * 512 + ((ks * 64 + g * 16) ^ ((i & 7) << 4));
      uint4 sfu = *reinterpret_cast<const uint4*>(&S4[byte >> 2]);
      bf16x8 sf = asb(sfu);
      #pragma unroll
      for (int dt = 0; dt < 4; ++dt){
        size_t vrow = (size_t)(bh * DD + dt * 16 + l15);
        uint4 vfu = vTu[vrow * 512 + c * 32 + ks * 4 + g];
        acc[dt] = __builtin_amdgcn_mfma_f32_16x16x32_bf16(asb(vfu), sf, acc[dt], 0, 0, 0);
      }
      uint4 of = (l15 == 0) ? ones4 : zero4;
      acc[4] = __builtin_amdgcn_mfma_f32_16x16x32_bf16(asb(of), sf, acc[4], 0, 0, 0);
    }
    #pragma unroll
    for (int ks = 0; ks < 8; ++ks){
      bf16x8 qb = asb(qf[t][ks]);
      #pragma unroll
      for (int dt = 0; dt < 4; ++dt){
        size_t prow = (size_t)(blk * DD + dt * 16 + l15);
        acc[dt] = __builtin_amdgcn_mfma_f32_16x16x32_bf16(asb(Spu[prow * 32 + ks * 4 + g]), qb, acc[dt], 0, 0, 0);
      }
      uint4 zf = (l15 == 0) ? zbu[blk * 32 + ks * 4 + g] : zero4;
      acc[4] = __builtin_amdgcn_mfma_f32_16x16x32_bf16(asb(zf), qb, acc[4], 0, 0, 0);
    }
    float den = __shfl(acc[4][0], l15, 64);
    float inv = 1.f / den;
    size_t obase = ((size_t)(b * LL + c * CC + i)) * EE + h * DD;
    #pragma unroll
    for (int dt = 0; dt < 4; ++dt){
      float4 o;
      o.x = acc[dt][0] * inv; o.y = acc[dt][1] * inv;
      o.z = acc[dt][2] * inv; o.w = acc[dt][3] * inv;
      *reinterpret_cast<float4*>(attn + obase + dt * 16 + g * 4) = o;
    }
  }
}

// ---------------- K7: out = attn[BL,E] @ Wout^T + bout ----------------
__global__ __launch_bounds__(256) void k_proj(const float* __restrict__ attn,
                                              const float* __restrict__ Wout,
                                              const float* __restrict__ bout,
                                              float* __restrict__ out){
  __shared__ float As[64][65];
  __shared__ float Bs[64][65];
  int rb = blockIdx.x >> 3, eb = blockIdx.x & 7;
  int r0 = rb * 64, e0 = eb * 64;
  int tid = threadIdx.x;
  int tx = tid & 15, ty = tid >> 4;
  float acc[4][4] = {};
  for (int k0 = 0; k0 < EE; k0 += 64){
    __syncthreads();
    for (int idx = tid; idx < 4096; idx += 256){
      int r = idx >> 6, kk = idx & 63;
      As[r][kk] = attn[(size_t)(r0 + r) * EE + k0 + kk];
    }
    for (int idx = tid; idx < 4096; idx += 256){
      int e = idx >> 6, kk = idx & 63;
      Bs[kk][e] = Wout[(size_t)(e0 + e) * EE + k0 + kk];
    }
    __syncthreads();
    #pragma unroll 8
    for (int kk = 0; kk < 64; ++kk){
      float a[4], bv[4];
      #pragma unroll
      for (int ii = 0; ii < 4; ++ii) a[ii] = As[ty * 4 + ii][kk];
      #pragma unroll
      for (int jj = 0; jj < 4; ++jj) bv[jj] = Bs[kk][jj * 16 + tx];
      #pragma unroll
      for (int ii = 0; ii < 4; ++ii)
        #pragma unroll
        for (int jj = 0; jj < 4; ++jj)
          acc[ii][jj] += a[ii] * bv[jj];
    }
  }
  #pragma unroll
  for (int ii = 0; ii < 4; ++ii){
    int r = r0 + ty * 4 + ii;
    #pragma unroll
    for (int jj = 0; jj < 4; ++jj){
      int e = e0 + jj * 16 + tx;
      out[(size_t)r * EE + e] = acc[ii][jj] + bout[e];
    }
  }
}

extern "C" void kernel_launch(void* const* d_in, const int* in_sizes, int n_in,
                              void* d_out, int out_size, void* d_ws, size_t ws_size,
                              hipStream_t stream){
  const float* queries = (const float*)d_in[0];
  const float* keys    = (const float*)d_in[1];
  const float* values  = (const float*)d_in[2];
  const float* Wq      = (const float*)d_in[3];
  const float* Wk      = (const float*)d_in[4];
  const float* Wv      = (const float*)d_in[5];
  const float* Wout    = (const float*)d_in[6];
  const float* bout    = (const float*)d_in[7];
  const float* proj    = (const float*)d_in[8];

  // workspace layout (~236 MiB with aliasing)
  char* ws = (char*)d_ws;
  float*          qh   = (float*)(ws + 0);                   // 33,554,432  [BH,L,D] f32
  float*          kh   = (float*)(ws + 33554432);            // 33,554,432
  unsigned short* vTb  = (unsigned short*)(ws + 67108864);   // 16,777,216  [BH,D,L] bf16
  unsigned short* qp   = (unsigned short*)(ws + 83886080);   // 67,108,864  [BH,L,M] bf16
  unsigned short* kp   = (unsigned short*)(ws + 150994944);  // 67,108,864
  unsigned short* Spb  = (unsigned short*)(ws + 218103808);  // 16,777,216  [BH,NCH,D,M] bf16
  float*          z    = (float*)(ws + 234881024);           // 524,288     [BH,NCH,M] f32
  unsigned short* zb   = (unsigned short*)(ws + 235405312);  // 262,144
  unsigned*       kmax = (unsigned*)(ws + 235667456);        // 4
  float*          SpT  = kh;   // kh dead after k_phi(kh)    [BH,NCH,D,M] f32
  float*          attn = qh;   // qh dead after k_phi(qh)    [B,L,E] f32
  float*          out  = (float*)d_out;

  hipMemsetAsync(kmax, 0, 4, stream);

  k_transform<<<dim3(BHN * LL / 4), dim3(256), 0, stream>>>(queries, Wq, qh);
  k_transform<<<dim3(BHN * LL / 4), dim3(256), 0, stream>>>(keys,    Wk, kh);
  k_transform_vT<<<dim3(BHN * (LL / 64)), dim3(256), 0, stream>>>(values, Wv, vTb);

  k_kmax<<<dim3(2048), dim3(256), 0, stream>>>(kh, proj, kmax);

  k_phi<<<dim3(2048), dim3(256), 0, stream>>>(qh, proj, kmax, qp, 1);
  k_phi<<<dim3(2048), dim3(256), 0, stream>>>(kh, proj, kmax, kp, 0);

  k_chunkKV_T<<<dim3(BHN * NCH), dim3(256), 0, stream>>>(kp, vTb, SpT);
  k_chunkZ<<<dim3(BHN * NCH), dim3(256), 0, stream>>>(kp, z);

  k_prefix_b<<<dim3((BHN * DD * MM) / 256), dim3(256), 0, stream>>>(SpT, Spb, DD * MM);
  k_prefix_b<<<dim3((BHN * MM) / 256), dim3(256), 0, stream>>>(z, zb, MM);

  k_cattn<<<dim3(BHN * NCH), dim3(512), 0, stream>>>(qp, kp, vTb, Spb, zb, attn);

  k_proj<<<dim3((BB * LL / 64) * (EE / 64)), dim3(256), 0, stream>>>(attn, Wout, bout, out);
}

// Round 3
// 740.411 us; speedup vs baseline: 4.8665x; 3.1217x over previous
//
#include <hip/hip_runtime.h>
#include <hip/hip_bf16.h>

// Performer (FAVOR+) causal linear self-attention, MI355X round 2.
// B=4 L=4096 E=512 H=8 D=64 M=256 chunk=256.
// Round 2: MFMA for phi/kmax, chunkKV (via kp transpose), out-proj.

#define BB 4
#define LL 4096
#define EE 512
#define HH 8
#define DD 64
#define MM 256
#define CC 256
#define NCH 16   // L / CC
#define BHN 32   // B * H

constexpr float DN    = 0.35355339059327373f; // 64^-0.25
constexpr float DIAGC = 0.0625f;              // 0.5 * dn^2
constexpr float RATIO = 0.0625f;              // 256^-0.5
constexpr float EPSV  = 1e-4f;

typedef __attribute__((ext_vector_type(8))) short bf16x8;
typedef __attribute__((ext_vector_type(4))) float f32x4;
union FU { uint4 u; bf16x8 b; };
__device__ __forceinline__ bf16x8 asb(uint4 u){ FU f; f.u = u; return f.b; }
union PK2 { ushort4 s; uint2 u; };
union PK8 { unsigned short s[8]; uint4 u; };

__device__ __forceinline__ unsigned short f2bf(float f){
  unsigned u = __float_as_uint(f);
  u = u + 0x7FFFu + ((u >> 16) & 1u);   // RTNE
  return (unsigned short)(u >> 16);
}
__device__ __forceinline__ float bfl(unsigned u){ return __uint_as_float(u << 16); }
__device__ __forceinline__ unsigned enc_f32(float f){
  unsigned u = __float_as_uint(f);
  return (u & 0x80000000u) ? ~u : (u | 0x80000000u);
}
__device__ __forceinline__ float dec_f32(unsigned u){
  unsigned v = (u & 0x80000000u) ? (u & 0x7FFFFFFFu) : ~u;
  return __uint_as_float(v);
}
__device__ __forceinline__ uint4 pack8(float4 a, float4 b){
  PK8 p;
  p.s[0] = f2bf(a.x); p.s[1] = f2bf(a.y); p.s[2] = f2bf(a.z); p.s[3] = f2bf(a.w);
  p.s[4] = f2bf(b.x); p.s[5] = f2bf(b.y); p.s[6] = f2bf(b.z); p.s[7] = f2bf(b.w);
  return p.u;
}

// ---------------- K1: head-split + per-head DxD projection (f32 out, for q,k) ----------------
__global__ __launch_bounds__(256) void k_transform(const float* __restrict__ x,
                                                   const float* __restrict__ W,
                                                   float* __restrict__ out){
  __shared__ float Wt[DD * 65];   // Wt[dp*65+d] = W[d][dp]
  __shared__ float xr[4][DD];
  int tid = threadIdx.x;
  for (int i = tid; i < DD * DD; i += 256){
    int d = i >> 6, dp = i & 63;
    Wt[dp * 65 + d] = W[i];
  }
  int bh = blockIdx.x >> 10;
  int l0 = (blockIdx.x & 1023) << 2;
  int b = bh >> 3, h = bh & 7;
  int r = tid >> 6, d = tid & 63;
  xr[r][d] = x[((size_t)(b * LL + l0 + r)) * EE + h * DD + d];
  __syncthreads();
  float acc = 0.f;
  #pragma unroll
  for (int dp = 0; dp < DD; ++dp)
    acc += xr[r][dp] * Wt[dp * 65 + d];
  out[((size_t)(bh * LL + l0 + r)) * DD + d] = acc;
}

// ---------------- K1v: v transform -> transposed bf16 vT [BH][D][L] ----------------
__global__ __launch_bounds__(256) void k_transform_vT(const float* __restrict__ x,
                                                      const float* __restrict__ W,
                                                      unsigned short* __restrict__ vTb){
  __shared__ float Wt[DD * 65];
  __shared__ float T[64 * 65];     // T[l][d], stride 65
  int tid = threadIdx.x;
  for (int i = tid; i < DD * DD; i += 256){
    int d = i >> 6, dp = i & 63;
    Wt[dp * 65 + d] = W[i];
  }
  __syncthreads();
  int bh = blockIdx.x >> 6;               // grid = BH * (L/64)
  int l0 = (blockIdx.x & 63) << 6;
  int b = bh >> 3, h = bh & 7;
  int r = tid >> 6, lane = tid & 63;
  for (int g = 0; g < 16; ++g){
    int l = g * 4 + r;
    float xv = x[((size_t)(b * LL + l0 + l)) * EE + h * DD + lane];
    float acc = 0.f;
    #pragma unroll
    for (int dp = 0; dp < DD; ++dp)
      acc += __shfl(xv, dp, 64) * Wt[dp * 65 + lane];
    T[l * 65 + lane] = acc;
  }
  __syncthreads();
  int dd = tid >> 2, e0 = (tid & 3) << 4;
  PK8 p0, p1;
  #pragma unroll
  for (int jj = 0; jj < 8; ++jj){
    p0.s[jj] = f2bf(T[(e0 + jj) * 65 + dd]);
    p1.s[jj] = f2bf(T[(e0 + 8 + jj) * 65 + dd]);
  }
  uint4* op = reinterpret_cast<uint4*>(vTb + ((size_t)(bh * DD + dd)) * LL + l0 + e0);
  op[0] = p0.u;
  op[1] = p1.u;
}

// ---------------- K2: MFMA phi / kmax ----------------
// mode 0: global max of xd(k) -> atomicMax(kmaxp). mode 1: query phi. mode 2: key phi.
// xd[row][m] = sum_d xh_bf16[row][d] * bf16(dn*proj[m][d]), MFMA 16x16x32.
__global__ __launch_bounds__(256) void k_phiM(const float* __restrict__ xh,
                                              const float* __restrict__ proj,
                                              unsigned* __restrict__ kmaxp,
                                              unsigned short* __restrict__ phi,
                                              int mode){
  __shared__ unsigned short Pl[256 * 64];   // swizzled bf16 dn*proj, 32 KiB
  int tid = threadIdx.x;
  // stage proj: chunk idx = m*8 + c; chunk = 8 bf16 = 16 B
  const float4* proj4 = reinterpret_cast<const float4*>(proj);
  for (int idx = tid; idx < 2048; idx += 256){
    int m = idx >> 3, c = idx & 7;
    float4 a = proj4[m * 16 + c * 2];
    float4 b = proj4[m * 16 + c * 2 + 1];
    a.x *= DN; a.y *= DN; a.z *= DN; a.w *= DN;
    b.x *= DN; b.y *= DN; b.z *= DN; b.w *= DN;
    int byte = m * 128 + ((c * 16) ^ ((m & 7) << 4));
    *reinterpret_cast<uint4*>(reinterpret_cast<char*>(Pl) + byte) = pack8(a, b);
  }
  __syncthreads();
  int w = tid >> 6, lane = tid & 63, l15 = lane & 15, g = lane >> 4;
  const float4* xh4 = reinterpret_cast<const float4*>(xh);
  float gmax = -3.0e38f;
  float gm = (mode == 2) ? dec_f32(*kmaxp) : 0.f;
  for (int rb = blockIdx.x * 4 + w; rb < (BHN * LL) / 16; rb += gridDim.x * 4){
    size_t row = (size_t)rb * 16 + l15;
    float4 a0 = xh4[row * 16 + g * 2];
    float4 a1 = xh4[row * 16 + g * 2 + 1];
    float4 b0 = xh4[row * 16 + 8 + g * 2];
    float4 b1 = xh4[row * 16 + 8 + g * 2 + 1];
    float ss = a0.x*a0.x + a0.y*a0.y + a0.z*a0.z + a0.w*a0.w
             + a1.x*a1.x + a1.y*a1.y + a1.z*a1.z + a1.w*a1.w
             + b0.x*b0.x + b0.y*b0.y + b0.z*b0.z + b0.w*b0.w
             + b1.x*b1.x + b1.y*b1.y + b1.z*b1.z + b1.w*b1.w;
    ss += __shfl_xor(ss, 16, 64);
    ss += __shfl_xor(ss, 32, 64);
    float diag = DIAGC * ss;
    bf16x8 A0 = asb(pack8(a0, a1));
    bf16x8 A1 = asb(pack8(b0, b1));
    f32x4 acc[16];
    #pragma unroll
    for (int mt = 0; mt < 16; ++mt){
      int r = mt * 16 + l15;
      int byte0 = r * 128 + ((g * 16) ^ ((l15 & 7) << 4));
      int byte1 = r * 128 + ((64 + g * 16) ^ ((l15 & 7) << 4));
      uint4 x0 = *reinterpret_cast<const uint4*>(reinterpret_cast<const char*>(Pl) + byte0);
      uint4 x1 = *reinterpret_cast<const uint4*>(reinterpret_cast<const char*>(Pl) + byte1);
      f32x4 z4 = {0.f, 0.f, 0.f, 0.f};
      z4 = __builtin_amdgcn_mfma_f32_16x16x32_bf16(asb(x0), A0, z4, 0, 0, 0);
      acc[mt] = __builtin_amdgcn_mfma_f32_16x16x32_bf16(asb(x1), A1, z4, 0, 0, 0);
    }
    if (mode == 0){
      float mx = -3.0e38f;
      #pragma unroll
      for (int mt = 0; mt < 16; ++mt)
        mx = fmaxf(mx, fmaxf(fmaxf(acc[mt][0], acc[mt][1]), fmaxf(acc[mt][2], acc[mt][3])));
      gmax = fmaxf(gmax, mx);
    } else {
      float msub;
      if (mode == 1){
        float mx = -3.0e38f;
        #pragma unroll
        for (int mt = 0; mt < 16; ++mt)
          mx = fmaxf(mx, fmaxf(fmaxf(acc[mt][0], acc[mt][1]), fmaxf(acc[mt][2], acc[mt][3])));
        mx = fmaxf(mx, __shfl_xor(mx, 16, 64));
        mx = fmaxf(mx, __shfl_xor(mx, 32, 64));
        msub = mx;
      } else {
        msub = gm;
      }
      float bsub = diag + msub;
      #pragma unroll
      for (int mt = 0; mt < 16; ++mt){
        ushort4 pk;
        pk.x = f2bf(RATIO * (expf(acc[mt][0] - bsub) + EPSV));
        pk.y = f2bf(RATIO * (expf(acc[mt][1] - bsub) + EPSV));
        pk.z = f2bf(RATIO * (expf(acc[mt][2] - bsub) + EPSV));
        pk.w = f2bf(RATIO * (expf(acc[mt][3] - bsub) + EPSV));
        *reinterpret_cast<ushort4*>(phi + row * MM + mt * 16 + g * 4) = pk;
      }
    }
  }
  if (mode == 0){
    #pragma unroll
    for (int off = 32; off >= 1; off >>= 1)
      gmax = fmaxf(gmax, __shfl_xor(gmax, off, 64));
    if (lane == 0) atomicMax(kmaxp, enc_f32(gmax));
  }
}

// ---------------- K3: transpose kp [BH*L][M] -> kpT [BH][M][L] ----------------
__global__ __launch_bounds__(256) void k_transpose(const unsigned short* __restrict__ kp,
                                                   unsigned short* __restrict__ kpT){
  __shared__ unsigned short T[64][72];
  int blk = blockIdx.x;                // bh(32) x lt(64) x mt(4)
  int bh = blk >> 8, rest = blk & 255;
  int lt = rest >> 2, mt = rest & 3;
  int l0 = lt * 64, m0 = mt * 64;
  int tid = threadIdx.x;
  {
    int r = tid >> 2, cq = tid & 3;
    const uint4* src = reinterpret_cast<const uint4*>(
        kp + ((size_t)(bh * LL) + l0 + r) * MM + m0 + cq * 16);
    uint4 v0 = src[0], v1 = src[1];
    *reinterpret_cast<uint4*>(&T[r][cq * 16]) = v0;
    *reinterpret_cast<uint4*>(&T[r][cq * 16 + 8]) = v1;
  }
  __syncthreads();
  {
    int m = tid >> 2, lq = tid & 3;
    PK8 p0, p1;
    #pragma unroll
    for (int j = 0; j < 8; ++j){
      p0.s[j] = T[lq * 16 + j][m];
      p1.s[j] = T[lq * 16 + 8 + j][m];
    }
    uint4* dst = reinterpret_cast<uint4*>(
        kpT + ((size_t)(bh * MM) + m0 + m) * LL + l0 + lq * 16);
    dst[0] = p0.u;
    dst[1] = p1.u;
  }
}

// ---------------- K4: MFMA per-chunk SpT_c[d][m] = sum_j vT[d,j] kpT[m,j]; z via ones ----
__global__ __launch_bounds__(256) void k_chunkKV_M(const unsigned short* __restrict__ kpT,
                                                   const unsigned short* __restrict__ vTb,
                                                   unsigned short* __restrict__ SpTc,
                                                   float* __restrict__ z){
  int tid = threadIdx.x;
  int w = tid >> 6, lane = tid & 63, l15 = lane & 15, g = lane >> 4;
  int blk = blockIdx.x;
  int bh = blk >> 4, c = blk & 15;
  const uint4* kT4 = reinterpret_cast<const uint4*>(kpT);
  const uint4* vT4 = reinterpret_cast<const uint4*>(vTb);
  uint4 zero4 = {0u, 0u, 0u, 0u};
  uint4 ones4 = {0x3F803F80u, 0x3F803F80u, 0x3F803F80u, 0x3F803F80u};
  uint4 onesf = (l15 == 0) ? ones4 : zero4;
  #pragma unroll
  for (int mi = 0; mi < 4; ++mi){
    int m0 = (w * 4 + mi) * 16;
    f32x4 acc[4];
    #pragma unroll
    for (int dt = 0; dt < 4; ++dt) acc[dt] = (f32x4){0.f, 0.f, 0.f, 0.f};
    f32x4 accz = {0.f, 0.f, 0.f, 0.f};
    for (int ks = 0; ks < 8; ++ks){
      uint4 kf = kT4[(((size_t)(bh * MM) + m0 + l15) * LL + c * CC + ks * 32 + g * 8) >> 3];
      #pragma unroll
      for (int dt = 0; dt < 4; ++dt){
        uint4 vf = vT4[(((size_t)(bh * DD) + dt * 16 + l15) * LL + c * CC + ks * 32 + g * 8) >> 3];
        acc[dt] = __builtin_amdgcn_mfma_f32_16x16x32_bf16(asb(kf), asb(vf), acc[dt], 0, 0, 0);
      }
      accz = __builtin_amdgcn_mfma_f32_16x16x32_bf16(asb(kf), asb(onesf), accz, 0, 0, 0);
    }
    #pragma unroll
    for (int dt = 0; dt < 4; ++dt){
      ushort4 pk;
      pk.x = f2bf(acc[dt][0]); pk.y = f2bf(acc[dt][1]);
      pk.z = f2bf(acc[dt][2]); pk.w = f2bf(acc[dt][3]);
      *reinterpret_cast<ushort4*>(SpTc + ((size_t)blk * DD + dt * 16 + l15) * MM + m0 + g * 4) = pk;
    }
    if (l15 == 0){
      float4 o; o.x = accz[0]; o.y = accz[1]; o.z = accz[2]; o.w = accz[3];
      *reinterpret_cast<float4*>(z + (size_t)blk * MM + m0 + g * 4) = o;
    }
  }
}

// ---------------- K5: exclusive prefix over chunks ----------------
__global__ __launch_bounds__(256) void k_prefix_b(const float* __restrict__ buf,
                                                  unsigned short* __restrict__ outb,
                                                  int per_bh){
  int idx = blockIdx.x * 256 + threadIdx.x;
  if (idx >= BHN * per_bh) return;
  int bh = idx / per_bh, r = idx - bh * per_bh;
  float run = 0.f;
  #pragma unroll
  for (int c = 0; c < NCH; ++c){
    size_t a = ((size_t)bh * NCH + c) * per_bh + r;
    outb[a] = f2bf(run);
    run += buf[a];
  }
}
__global__ __launch_bounds__(256) void k_prefix_bb(const unsigned short* __restrict__ buf,
                                                   unsigned short* __restrict__ outb,
                                                   int per_bh){
  int idx = blockIdx.x * 256 + threadIdx.x;
  if (idx >= BHN * per_bh) return;
  int bh = idx / per_bh, r = idx - bh * per_bh;
  float run = 0.f;
  #pragma unroll
  for (int c = 0; c < NCH; ++c){
    size_t a = ((size_t)bh * NCH + c) * per_bh + r;
    outb[a] = f2bf(run);
    run += bfl((unsigned)buf[a]);
  }
}

// ---------------- K6: MFMA chunk causal attention (bf16 attn out) ----------------
__global__ __launch_bounds__(512, 2) void k_cattn(const unsigned short* __restrict__ qp,
                                                  const unsigned short* __restrict__ kp,
                                                  const unsigned short* __restrict__ vTb,
                                                  const unsigned short* __restrict__ Spb,
                                                  const unsigned short* __restrict__ zb,
                                                  unsigned short* __restrict__ attnb){
  __shared__ unsigned S4[CC * 128];   // 128 KiB: S[i][j] bf16, byte ^= ((i&7)<<4)
  int tid = threadIdx.x;
  int w = tid >> 6, lane = tid & 63;
  int l15 = lane & 15, g = lane >> 4;
  int blk = blockIdx.x;
  int bh = blk >> 4, c = blk & 15;
  int b = bh >> 3, h = bh & 7;
  size_t row0 = (size_t)blk * CC;
  const uint4* qpu = reinterpret_cast<const uint4*>(qp);
  const uint4* kpu = reinterpret_cast<const uint4*>(kp);
  const uint4* vTu = reinterpret_cast<const uint4*>(vTb);
  const uint4* Spu = reinterpret_cast<const uint4*>(Spb);
  const uint4* zbu = reinterpret_cast<const uint4*>(zb);

  int its[2] = { w, 15 - w };
  uint4 qf[2][8];
  #pragma unroll
  for (int t = 0; t < 2; ++t){
    size_t qrow = row0 + its[t] * 16 + l15;
    #pragma unroll
    for (int ks = 0; ks < 8; ++ks)
      qf[t][ks] = qpu[qrow * 32 + ks * 4 + g];
  }

  // ---- phase 1: scores ----
  #pragma unroll
  for (int t = 0; t < 2; ++t){
    int it = its[t];
    int i = it * 16 + l15;
    int jtmax = it | 1;
    for (int jt = 0; jt <= jtmax; ++jt){
      f32x4 acc = {0.f, 0.f, 0.f, 0.f};
      size_t krow = row0 + jt * 16 + l15;
      #pragma unroll
      for (int ks = 0; ks < 8; ++ks){
        uint4 kfu = kpu[krow * 32 + ks * 4 + g];
        acc = __builtin_amdgcn_mfma_f32_16x16x32_bf16(asb(kfu), asb(qf[t][ks]), acc, 0, 0, 0);
      }
      int jb = jt * 16 + g * 4;
      PK2 pk;
      pk.s.x = (jb + 0 <= i) ? f2bf(acc[0]) : (unsigned short)0;
      pk.s.y = (jb + 1 <= i) ? f2bf(acc[1]) : (unsigned short)0;
      pk.s.z = (jb + 2 <= i) ? f2bf(acc[2]) : (unsigned short)0;
      pk.s.w = (jb + 3 <= i) ? f2bf(acc[3]) : (unsigned short)0;
      int byte = i * 512 + ((jb * 2) ^ ((i & 7) << 4));
      *reinterpret_cast<uint2*>(&S4[byte >> 2]) = pk.u;
    }
  }
  // no barrier: each wave reads only S rows it wrote.

  // ---- phase 2: PV + prefix ----
  uint4 zero4 = {0u, 0u, 0u, 0u};
  uint4 ones4 = {0x3F803F80u, 0x3F803F80u, 0x3F803F80u, 0x3F803F80u};
  #pragma unroll
  for (int t = 0; t < 2; ++t){
    int it = its[t];
    int i = it * 16 + l15;
    f32x4 acc[5];
    #pragma unroll
    for (int a5 = 0; a5 < 5; ++a5) acc[a5] = (f32x4){0.f, 0.f, 0.f, 0.f};
    int ksv = (it >> 1) + 1;
    for (int ks = 0; ks < ksv; ++ks){
      int byte = i * 512 + ((ks * 64 + g * 16) ^ ((i & 7) << 4));
      uint4 sfu = *reinterpret_cast<const uint4*>(&S4[byte >> 2]);
      bf16x8 sf = asb(sfu);
      #pragma unroll
      for (int dt = 0; dt < 4; ++dt){
        size_t vrow = (size_t)(bh * DD + dt * 16 + l15);
        uint4 vfu = vTu[vrow * 512 + c * 32 + ks * 4 + g];
        acc[dt] = __builtin_amdgcn_mfma_f32_16x16x32_bf16(asb(vfu), sf, acc[dt], 0, 0, 0);
      }
      uint4 of = (l15 == 0) ? ones4 : zero4;
      acc[4] = __builtin_amdgcn_mfma_f32_16x16x32_bf16(asb(of), sf, acc[4], 0, 0, 0);
    }
    #pragma unroll
    for (int ks = 0; ks < 8; ++ks){
      bf16x8 qb = asb(qf[t][ks]);
      #pragma unroll
      for (int dt = 0; dt < 4; ++dt){
        size_t prow = (size_t)(blk * DD + dt * 16 + l15);
        acc[dt] = __builtin_amdgcn_mfma_f32_16x16x32_bf16(asb(Spu[prow * 32 + ks * 4 + g]), qb, acc[dt], 0, 0, 0);
      }
      uint4 zf = (l15 == 0) ? zbu[blk * 32 + ks * 4 + g] : zero4;
      acc[4] = __builtin_amdgcn_mfma_f32_16x16x32_bf16(asb(zf), qb, acc[4], 0, 0, 0);
    }
    float den = __shfl(acc[4][0], l15, 64);
    float inv = 1.f / den;
    size_t obase = ((size_t)(b * LL + c * CC + i)) * EE + h * DD;
    #pragma unroll
    for (int dt = 0; dt < 4; ++dt){
      ushort4 pk;
      pk.x = f2bf(acc[dt][0] * inv); pk.y = f2bf(acc[dt][1] * inv);
      pk.z = f2bf(acc[dt][2] * inv); pk.w = f2bf(acc[dt][3] * inv);
      *reinterpret_cast<ushort4*>(attnb + obase + dt * 16 + g * 4) = pk;
    }
  }
}

// ---------------- K7a: Wout f32 -> bf16 ----------------
__global__ __launch_bounds__(256) void k_cvtW(const float* __restrict__ W,
                                              unsigned short* __restrict__ Wb){
  int idx = blockIdx.x * 256 + threadIdx.x;   // 0..131071 (pairs)
  float2 v = reinterpret_cast<const float2*>(W)[idx];
  unsigned u = ((unsigned)f2bf(v.y) << 16) | (unsigned)f2bf(v.x);
  reinterpret_cast<unsigned*>(Wb)[idx] = u;
}

// ---------------- K7: MFMA out-proj: out = attnb @ Woutb^T + bout ----------------
__global__ __launch_bounds__(256) void k_proj_M(const unsigned short* __restrict__ attnb,
                                                const unsigned short* __restrict__ Woutb,
                                                const float* __restrict__ bout,
                                                float* __restrict__ out){
  int tid = threadIdx.x;
  int w = tid >> 6, lane = tid & 63, l15 = lane & 15, g = lane >> 4;
  int rb = blockIdx.x >> 3, eb = blockIdx.x & 7;
  int r0 = rb * 64, e0 = eb * 64;
  int r = r0 + w * 16 + l15;
  const uint4* at4 = reinterpret_cast<const uint4*>(attnb);
  const uint4* Wo4 = reinterpret_cast<const uint4*>(Woutb);
  f32x4 acc[4];
  #pragma unroll
  for (int ct = 0; ct < 4; ++ct) acc[ct] = (f32x4){0.f, 0.f, 0.f, 0.f};
  for (int ks = 0; ks < 16; ++ks){
    uint4 bfrag = at4[((size_t)r * EE + ks * 32 + g * 8) >> 3];
    #pragma unroll
    for (int ct = 0; ct < 4; ++ct){
      uint4 af = Wo4[((size_t)(e0 + ct * 16 + l15) * EE + ks * 32 + g * 8) >> 3];
      acc[ct] = __builtin_amdgcn_mfma_f32_16x16x32_bf16(asb(af), asb(bfrag), acc[ct], 0, 0, 0);
    }
  }
  #pragma unroll
  for (int ct = 0; ct < 4; ++ct){
    int e = e0 + ct * 16 + g * 4;
    float4 bo = *reinterpret_cast<const float4*>(bout + e);
    float4 o;
    o.x = acc[ct][0] + bo.x; o.y = acc[ct][1] + bo.y;
    o.z = acc[ct][2] + bo.z; o.w = acc[ct][3] + bo.w;
    *reinterpret_cast<float4*>(out + (size_t)r * EE + e) = o;
  }
}

extern "C" void kernel_launch(void* const* d_in, const int* in_sizes, int n_in,
                              void* d_out, int out_size, void* d_ws, size_t ws_size,
                              hipStream_t stream){
  const float* queries = (const float*)d_in[0];
  const float* keys    = (const float*)d_in[1];
  const float* values  = (const float*)d_in[2];
  const float* Wq      = (const float*)d_in[3];
  const float* Wk      = (const float*)d_in[4];
  const float* Wv      = (const float*)d_in[5];
  const float* Wout    = (const float*)d_in[6];
  const float* bout    = (const float*)d_in[7];
  const float* proj    = (const float*)d_in[8];

  // workspace layout (~236.2 MiB with aliasing)
  char* ws = (char*)d_ws;
  float*          qh   = (float*)(ws + 0);                   // 33.5M [BH,L,D] f32
  float*          kh   = (float*)(ws + 33554432);            // 33.5M
  unsigned short* vTb  = (unsigned short*)(ws + 67108864);   // 16.8M [BH,D,L] bf16
  unsigned short* qp   = (unsigned short*)(ws + 83886080);   // 67M   [BH,L,M] bf16
  unsigned short* kp   = (unsigned short*)(ws + 150994944);  // 67M
  unsigned short* SpTc = (unsigned short*)(ws + 218103808);  // 16.8M [BH,NCH,D,M] bf16 (per-chunk)
  float*          z    = (float*)(ws + 234881024);           // 0.5M  [BH,NCH,M] f32
  unsigned short* zb   = (unsigned short*)(ws + 235405312);  // 0.26M
  unsigned short* Woutb= (unsigned short*)(ws + 235667456);  // 0.5M  [E,E] bf16
  unsigned*       kmax = (unsigned*)(ws + 236191744);        // 4
  // aliases (lifetime-disjoint):
  unsigned short* kpT  = (unsigned short*)(ws + 0);          // 67M over dead qh+kh
  unsigned short* Spb  = (unsigned short*)(ws + 0);          // 16.8M over dead kpT
  unsigned short* attnb= (unsigned short*)(ws + 16777216);   // 16.8M [B,L,E] bf16
  float*          out  = (float*)d_out;

  hipMemsetAsync(kmax, 0, 4, stream);

  k_transform<<<dim3(BHN * LL / 4), dim3(256), 0, stream>>>(queries, Wq, qh);
  k_transform<<<dim3(BHN * LL / 4), dim3(256), 0, stream>>>(keys,    Wk, kh);
  k_transform_vT<<<dim3(BHN * (LL / 64)), dim3(256), 0, stream>>>(values, Wv, vTb);
  k_cvtW<<<dim3(512), dim3(256), 0, stream>>>(Wout, Woutb);

  k_phiM<<<dim3(2048), dim3(256), 0, stream>>>(kh, proj, kmax, nullptr, 0);  // global kmax
  k_phiM<<<dim3(2048), dim3(256), 0, stream>>>(qh, proj, kmax, qp, 1);       // phi(q)
  k_phiM<<<dim3(2048), dim3(256), 0, stream>>>(kh, proj, kmax, kp, 2);       // phi(k)

  k_transpose<<<dim3(BHN * 256), dim3(256), 0, stream>>>(kp, kpT);
  k_chunkKV_M<<<dim3(BHN * NCH), dim3(256), 0, stream>>>(kpT, vTb, SpTc, z);

  k_prefix_bb<<<dim3((BHN * DD * MM) / 256), dim3(256), 0, stream>>>(SpTc, Spb, DD * MM);
  k_prefix_b<<<dim3((BHN * MM) / 256), dim3(256), 0, stream>>>(z, zb, MM);

  k_cattn<<<dim3(BHN * NCH), dim3(512), 0, stream>>>(qp, kp, vTb, Spb, zb, attnb);

  k_proj_M<<<dim3((BB * LL / 64) * (EE / 64)), dim3(256), 0, stream>>>(attnb, Woutb, bout, out);
}